// Round 2
// baseline (522.059 us; speedup 1.0000x reference)
//
#include <hip/hip_runtime.h>

#define N_NODES 50000
#define N_EDGES 1600000
#define D 32
#define SCAN_THREADS 1024
#define SCAN_CHUNK ((N_NODES + SCAN_THREADS - 1) / SCAN_THREADS)  // 49

// ---------------------------------------------------------------------------
// K1: zero int4-aligned region (degree histograms)
// ---------------------------------------------------------------------------
__global__ __launch_bounds__(256) void zero_kernel(int4* __restrict__ p, int n4) {
    int i = blockIdx.x * blockDim.x + threadIdx.x;
    if (i < n4) p[i] = make_int4(0, 0, 0, 0);
}

// ---------------------------------------------------------------------------
// K2: degree histograms (int atomics)
// ---------------------------------------------------------------------------
__global__ __launch_bounds__(256) void degree_kernel(const int* __restrict__ src,
                                                     const int* __restrict__ dst,
                                                     int* __restrict__ deg_out,
                                                     int* __restrict__ deg_in) {
    int e = blockIdx.x * blockDim.x + threadIdx.x;
    if (e < N_EDGES) {
        atomicAdd(&deg_out[src[e]], 1);
        atomicAdd(&deg_in[dst[e]], 1);
    }
}

// ---------------------------------------------------------------------------
// K3: exclusive scan of deg_in -> row_ptr[N+1], cursor := row_ptr copy.
// Single workgroup of 1024 threads; each owns a 49-element chunk.
// ---------------------------------------------------------------------------
__global__ __launch_bounds__(SCAN_THREADS) void scan_kernel(const int* __restrict__ deg_in,
                                                            int* __restrict__ row_ptr,
                                                            int* __restrict__ cursor) {
    __shared__ int part[SCAN_THREADS];
    int t = threadIdx.x;
    int begin = t * SCAN_CHUNK;
    int end = min(begin + SCAN_CHUNK, N_NODES);

    int s = 0;
    for (int i = begin; i < end; ++i) s += deg_in[i];
    part[t] = s;
    __syncthreads();

    // Hillis-Steele inclusive scan over 1024 partials
    for (int off = 1; off < SCAN_THREADS; off <<= 1) {
        int add = (t >= off) ? part[t - off] : 0;
        __syncthreads();
        part[t] += add;
        __syncthreads();
    }

    int run = (t == 0) ? 0 : part[t - 1];  // exclusive prefix of my chunk
    for (int i = begin; i < end; ++i) {
        row_ptr[i] = run;
        cursor[i] = run;
        run += deg_in[i];
    }
    if (t == SCAN_THREADS - 1) row_ptr[N_NODES] = part[SCAN_THREADS - 1];
}

// ---------------------------------------------------------------------------
// K4: norms from int degrees (zero-degree -> 0)
// ---------------------------------------------------------------------------
__global__ __launch_bounds__(256) void norm_kernel(const int* __restrict__ deg_out,
                                                   const int* __restrict__ deg_in,
                                                   float* __restrict__ norm_out,
                                                   float* __restrict__ norm_in) {
    int i = blockIdx.x * blockDim.x + threadIdx.x;
    if (i < N_NODES) {
        int d0 = deg_out[i];
        int d1 = deg_in[i];
        norm_out[i] = (d0 > 0) ? rsqrtf((float)d0) : 0.f;
        norm_in[i]  = (d1 > 0) ? rsqrtf((float)d1) : 0.f;
    }
}

// ---------------------------------------------------------------------------
// K5: counting-sort fill: sorted_src[slot] = src[e], slot = cursor[dst[e]]++
// ---------------------------------------------------------------------------
__global__ __launch_bounds__(256) void fill_kernel(const int* __restrict__ src,
                                                   const int* __restrict__ dst,
                                                   int* __restrict__ cursor,
                                                   int* __restrict__ sorted_src) {
    int e = blockIdx.x * blockDim.x + threadIdx.x;
    if (e < N_EDGES) {
        int pos = atomicAdd(&cursor[dst[e]], 1);
        sorted_src[pos] = src[e];
    }
}

// ---------------------------------------------------------------------------
// K6: xs[i,d] = x[i,d] * norm_out[i]   (coalesced)
// ---------------------------------------------------------------------------
__global__ __launch_bounds__(256) void scale_kernel(const float* __restrict__ x,
                                                    const float* __restrict__ norm_out,
                                                    float* __restrict__ xs) {
    int t = blockIdx.x * blockDim.x + threadIdx.x;
    if (t < N_NODES * D) {
        xs[t] = x[t] * norm_out[t >> 5];
    }
}

// ---------------------------------------------------------------------------
// K7/K8: fused gather-aggregate + norm_in + GEMM(32x32) + bias (+relu*norm_out).
// Block = 256 threads = 8 nodes x 32 features. No atomics, no agg buffer.
//   acc_j = sum_{e in CSR[n]} xs[src_e, j]          (coalesced 128B gathers)
//   val   = acc * norm_in[n]
//   o_j   = b[j] + sum_k val_k * W[k,j]
//   L1: out = relu(o) * norm_out[n]  (pre-scaled messages for layer 2)
//   L2: out = o                      (final)
// ---------------------------------------------------------------------------
template <int IS_L1>
__global__ __launch_bounds__(256) void aggregate_kernel(const int* __restrict__ row_ptr,
                                                        const int* __restrict__ sorted_src,
                                                        const float* __restrict__ xs,
                                                        const float* __restrict__ norm_in,
                                                        const float* __restrict__ norm_out,
                                                        const float* __restrict__ W,
                                                        const float* __restrict__ b,
                                                        float* __restrict__ out) {
    __shared__ float sW[D * D];
    __shared__ float sRow[8][D];

    int t = threadIdx.x;
    int r = t >> 5;   // local node 0..7
    int j = t & 31;   // feature
    int node = blockIdx.x * 8 + r;

    for (int k = t; k < D * D; k += 256) sW[k] = W[k];

    float acc = 0.f;
    if (node < N_NODES) {
        int beg = row_ptr[node];
        int end = row_ptr[node + 1];
#pragma unroll 4
        for (int e = beg; e < end; ++e) {
            int s = sorted_src[e];          // uniform across the 32-thread group
            acc += xs[s * D + j];           // coalesced 128B row gather
        }
        acc *= norm_in[node];
    }
    sRow[r][j] = acc;
    __syncthreads();

    if (node >= N_NODES) return;

    float o = b[j];
#pragma unroll
    for (int k = 0; k < D; ++k) o += sRow[r][k] * sW[k * D + j];

    if (IS_L1) o = fmaxf(o, 0.f) * norm_out[node];
    out[node * D + j] = o;
}

// ---------------------------------------------------------------------------
extern "C" void kernel_launch(void* const* d_in, const int* in_sizes, int n_in,
                              void* d_out, int out_size, void* d_ws, size_t ws_size,
                              hipStream_t stream) {
    const float* x  = (const float*)d_in[0];
    const int* src  = (const int*)d_in[1];
    const int* dst  = (const int*)d_in[2];
    const float* W1 = (const float*)d_in[3];
    const float* b1 = (const float*)d_in[4];
    const float* W2 = (const float*)d_in[5];
    const float* b2 = (const float*)d_in[6];
    float* out = (float*)d_out;

    // workspace layout (all offsets multiple of 4 elements -> 16B aligned)
    int* wsI = (int*)d_ws;
    int* deg_out_i   = wsI;                          // N
    int* deg_in_i    = deg_out_i + N_NODES;          // N   (contiguous with deg_out for zeroing)
    int* row_ptr     = deg_in_i + N_NODES;           // N+1 (padded to N+4)
    int* cursor      = row_ptr + N_NODES + 4;        // N
    int* sorted_src  = cursor + N_NODES;             // E
    float* norm_out  = (float*)(sorted_src + N_EDGES);  // N
    float* norm_in   = norm_out + N_NODES;           // N
    float* xs1       = norm_in + N_NODES;            // 32N
    float* xs2       = xs1 + N_NODES * D;            // 32N

    // K1: zero degree histograms (2N ints)
    {
        int n4 = (2 * N_NODES) / 4;
        zero_kernel<<<(n4 + 255) / 256, 256, 0, stream>>>((int4*)deg_out_i, n4);
    }
    // K2: degrees
    degree_kernel<<<(N_EDGES + 255) / 256, 256, 0, stream>>>(src, dst, deg_out_i, deg_in_i);
    // K3: scan -> row_ptr, cursor
    scan_kernel<<<1, SCAN_THREADS, 0, stream>>>(deg_in_i, row_ptr, cursor);
    // K4: norms
    norm_kernel<<<(N_NODES + 255) / 256, 256, 0, stream>>>(deg_out_i, deg_in_i, norm_out, norm_in);
    // K5: counting-sort edges by dst
    fill_kernel<<<(N_EDGES + 255) / 256, 256, 0, stream>>>(src, dst, cursor, sorted_src);
    // K6: xs1 = x * norm_out
    scale_kernel<<<(N_NODES * D + 255) / 256, 256, 0, stream>>>(x, norm_out, xs1);
    // K7: layer 1 fused aggregate -> xs2 holds relu(h1)*norm_out (layer-2 messages)
    aggregate_kernel<1><<<(N_NODES + 7) / 8, 256, 0, stream>>>(row_ptr, sorted_src, xs1,
                                                               norm_in, norm_out, W1, b1, xs2);
    // K8: layer 2 fused aggregate -> final output
    aggregate_kernel<0><<<(N_NODES + 7) / 8, 256, 0, stream>>>(row_ptr, sorted_src, xs2,
                                                               norm_in, norm_out, W2, b2, out);
}

// Round 3
// 230.999 us; speedup vs baseline: 2.2600x; 2.2600x over previous
//
#include <hip/hip_runtime.h>

#define N_NODES 50000
#define N_EDGES 1600000
#define D 32

#define NBUCKETS 256
#define NODES_PER_BUCKET 196   // ceil(50000/256); bucket = dst/196 in [0,255]
#define BUCKET_CAP 8192        // mean 6272, sigma ~79 -> +24 sigma headroom

#define HIST_BLOCKS 128
#define HIST_EPB (N_EDGES / HIST_BLOCKS)  // 12500
#define HWORDS 25000                      // 2 packed 16-bit counts per word

#define SCAT_BLOCKS 250
#define SCAT_EPB (N_EDGES / SCAT_BLOCKS)  // 6400 (= 25 iters of 256)

// ---------------------------------------------------------------------------
// K0: zero small int4 region (bucket cursors)
// ---------------------------------------------------------------------------
__global__ __launch_bounds__(64) void zero_small_kernel(int4* __restrict__ p, int n4) {
    int i = threadIdx.x;
    if (i < n4) p[i] = make_int4(0, 0, 0, 0);
}

// ---------------------------------------------------------------------------
// K1: out-degree histogram of src via packed LDS (2 x u16 per word).
// Per-block chunk = 12500 edges -> field max 12500 < 65536, no carry.
// ---------------------------------------------------------------------------
__global__ __launch_bounds__(256) void hist_src_kernel(const int* __restrict__ src,
                                                       unsigned int* __restrict__ dump) {
    __shared__ unsigned int h[HWORDS];  // 100 KB
    int t = threadIdx.x;
    for (int i = t; i < HWORDS; i += 256) h[i] = 0u;
    __syncthreads();
    int e0 = blockIdx.x * HIST_EPB;
    for (int i = t; i < HIST_EPB; i += 256) {
        int s = src[e0 + i];
        atomicAdd(&h[s >> 1], (s & 1) ? 65536u : 1u);  // LDS atomic, no return
    }
    __syncthreads();
    unsigned int* out = dump + (size_t)blockIdx.x * HWORDS;
    for (int i = t; i < HWORDS; i += 256) out[i] = h[i];
}

// ---------------------------------------------------------------------------
// K2: reduce per-block histograms -> norm_out = rsqrt(deg_out) (0 if deg==0)
// ---------------------------------------------------------------------------
__global__ __launch_bounds__(256) void reduce_normout_kernel(const unsigned int* __restrict__ dump,
                                                             float* __restrict__ norm_out) {
    int w = blockIdx.x * 256 + threadIdx.x;
    if (w >= HWORDS) return;
    unsigned int a0 = 0, a1 = 0;
    for (int b = 0; b < HIST_BLOCKS; ++b) {
        unsigned int v = dump[(size_t)b * HWORDS + w];
        a0 += v & 0xFFFFu;
        a1 += v >> 16;
    }
    norm_out[2 * w]     = a0 ? rsqrtf((float)a0) : 0.f;
    norm_out[2 * w + 1] = a1 ? rsqrtf((float)a1) : 0.f;
}

// ---------------------------------------------------------------------------
// K3: partition edges into 256 dst-range buckets.
// Ranks via LDS counters; ONE global atomic per (block,bucket) = ~64K total.
// ---------------------------------------------------------------------------
__global__ __launch_bounds__(256) void scatter_pairs_kernel(const int* __restrict__ src,
                                                            const int* __restrict__ dst,
                                                            int* __restrict__ bucket_cursor,
                                                            int2* __restrict__ pairbuf) {
    __shared__ int cnt[NBUCKETS];
    __shared__ int base[NBUCKETS];
    __shared__ unsigned short rank_lds[SCAT_EPB];  // 12.8 KB
    int t = threadIdx.x;
    int e0 = blockIdx.x * SCAT_EPB;
    if (t < NBUCKETS) cnt[t] = 0;
    __syncthreads();
#pragma unroll 5
    for (int i = 0; i < SCAT_EPB / 256; ++i) {
        int idx = i * 256 + t;
        int d = dst[e0 + idx];
        int k = d / NODES_PER_BUCKET;
        rank_lds[idx] = (unsigned short)atomicAdd(&cnt[k], 1);
    }
    __syncthreads();
    if (t < NBUCKETS) base[t] = atomicAdd(&bucket_cursor[t], cnt[t]);
    __syncthreads();
#pragma unroll 5
    for (int i = 0; i < SCAT_EPB / 256; ++i) {
        int idx = i * 256 + t;
        int s = src[e0 + idx];
        int d = dst[e0 + idx];
        int k = d / NODES_PER_BUCKET;
        int slot = base[k] + (int)rank_lds[idx];
        if (slot < BUCKET_CAP)  // safety guard (statistically impossible)
            pairbuf[(size_t)k * BUCKET_CAP + slot] = make_int2(s, d);
    }
}

// ---------------------------------------------------------------------------
// K4: exclusive scan of bucket sizes -> bucket output bases
// ---------------------------------------------------------------------------
__global__ __launch_bounds__(NBUCKETS) void bucket_scan_kernel(const int* __restrict__ bucket_cursor,
                                                               int* __restrict__ bucket_base) {
    __shared__ int a[NBUCKETS];
    int t = threadIdx.x;
    int v = bucket_cursor[t];
    a[t] = v;
    __syncthreads();
    for (int off = 1; off < NBUCKETS; off <<= 1) {
        int add = (t >= off) ? a[t - off] : 0;
        __syncthreads();
        a[t] += add;
        __syncthreads();
    }
    bucket_base[t] = a[t] - v;  // exclusive prefix
    if (t == NBUCKETS - 1) bucket_base[NBUCKETS] = a[t];
}

// ---------------------------------------------------------------------------
// K5: per-bucket exact counting sort (LDS cursors over 196 nodes).
// Emits row_ptr, norm_in, sorted_src. No global atomics.
// ---------------------------------------------------------------------------
__global__ __launch_bounds__(256) void sort_bucket_kernel(const int* __restrict__ bucket_cursor,
                                                          const int* __restrict__ bucket_base,
                                                          const int2* __restrict__ pairbuf,
                                                          int* __restrict__ row_ptr,
                                                          float* __restrict__ norm_in,
                                                          int* __restrict__ sorted_src) {
    __shared__ int cnt[256];
    __shared__ int scan[256];
    __shared__ int cur[NODES_PER_BUCKET];
    int k = blockIdx.x;
    int t = threadIdx.x;
    int lo = k * NODES_PER_BUCKET;
    int nb = min(NODES_PER_BUCKET, N_NODES - lo);  // last bucket: 20
    int size = bucket_cursor[k];
    int obase = bucket_base[k];
    const int2* pb = pairbuf + (size_t)k * BUCKET_CAP;

    cnt[t] = 0;
    __syncthreads();
    for (int i = t; i < size; i += 256) {
        atomicAdd(&cnt[pb[i].y - lo], 1);  // LDS, no return
    }
    __syncthreads();
    int v = cnt[t];
    scan[t] = v;
    __syncthreads();
    for (int off = 1; off < 256; off <<= 1) {
        int add = (t >= off) ? scan[t - off] : 0;
        __syncthreads();
        scan[t] += add;
        __syncthreads();
    }
    int excl = scan[t] - v;
    if (t < nb) {
        row_ptr[lo + t] = obase + excl;
        norm_in[lo + t] = (v > 0) ? rsqrtf((float)v) : 0.f;
        cur[t] = obase + excl;
    }
    if (k == NBUCKETS - 1 && t == 0) row_ptr[N_NODES] = N_EDGES;
    __syncthreads();
    for (int i = t; i < size; i += 256) {
        int2 p = pb[i];
        int slot = atomicAdd(&cur[p.y - lo], 1);  // LDS with return
        sorted_src[slot] = p.x;
    }
}

// ---------------------------------------------------------------------------
// K6: xs[i,d] = x[i,d] * norm_out[i]
// ---------------------------------------------------------------------------
__global__ __launch_bounds__(256) void scale_kernel(const float* __restrict__ x,
                                                    const float* __restrict__ norm_out,
                                                    float* __restrict__ xs) {
    int t = blockIdx.x * blockDim.x + threadIdx.x;
    if (t < N_NODES * D) {
        xs[t] = x[t] * norm_out[t >> 5];
    }
}

// ---------------------------------------------------------------------------
// K7/K8: fused gather-aggregate + norm_in + 32x32 GEMM + bias (+relu*norm_out)
// ---------------------------------------------------------------------------
template <int IS_L1>
__global__ __launch_bounds__(256) void aggregate_kernel(const int* __restrict__ row_ptr,
                                                        const int* __restrict__ sorted_src,
                                                        const float* __restrict__ xs,
                                                        const float* __restrict__ norm_in,
                                                        const float* __restrict__ norm_out,
                                                        const float* __restrict__ W,
                                                        const float* __restrict__ b,
                                                        float* __restrict__ out) {
    __shared__ float sW[D * D];
    __shared__ float sRow[8][D];

    int t = threadIdx.x;
    int r = t >> 5;   // local node 0..7
    int j = t & 31;   // feature
    int node = blockIdx.x * 8 + r;

    for (int k = t; k < D * D; k += 256) sW[k] = W[k];

    float acc = 0.f;
    if (node < N_NODES) {
        int beg = row_ptr[node];
        int end = row_ptr[node + 1];
#pragma unroll 4
        for (int e = beg; e < end; ++e) {
            int s = sorted_src[e];   // uniform across the 32-thread group
            acc += xs[s * D + j];    // coalesced 128B row gather
        }
        acc *= norm_in[node];
    }
    sRow[r][j] = acc;
    __syncthreads();

    if (node >= N_NODES) return;

    float o = b[j];
#pragma unroll
    for (int k = 0; k < D; ++k) o += sRow[r][k] * sW[k * D + j];

    if (IS_L1) o = fmaxf(o, 0.f) * norm_out[node];
    out[node * D + j] = o;
}

// ---------------------------------------------------------------------------
extern "C" void kernel_launch(void* const* d_in, const int* in_sizes, int n_in,
                              void* d_out, int out_size, void* d_ws, size_t ws_size,
                              hipStream_t stream) {
    const float* x  = (const float*)d_in[0];
    const int* src  = (const int*)d_in[1];
    const int* dst  = (const int*)d_in[2];
    const float* W1 = (const float*)d_in[3];
    const float* b1 = (const float*)d_in[4];
    const float* W2 = (const float*)d_in[5];
    const float* b2 = (const float*)d_in[6];
    float* out = (float*)d_out;

    // ---- workspace layout (int offsets; total ~36.6 MB) ----
    int*   wsI           = (int*)d_ws;
    float* norm_out      = (float*)wsI;                 // 50000
    float* norm_in       = (float*)(wsI + 50000);       // 50000
    int*   row_ptr       = wsI + 100000;                // 50001 (pad to 50016)
    int*   bucket_cursor = wsI + 150016;                // 256
    int*   bucket_base   = wsI + 150272;                // 257 (pad to 512)
    int*   sorted_src    = wsI + 150784;                // 1600000
    float* xs1           = (float*)(wsI + 1750784);     // 1600000 } alias with
    float* xs2           = (float*)(wsI + 3350784);     // 1600000 } hist dump
    unsigned int* dump   = (unsigned int*)(wsI + 1750784);  // 128*25000 = 3.2M words
    int2*  pairbuf       = (int2*)(wsI + 4950784);      // 256*8192 int2 = 16.8 MB

    // K0: zero bucket cursors (256 ints = 64 int4)
    zero_small_kernel<<<1, 64, 0, stream>>>((int4*)bucket_cursor, 64);
    // K1: src out-degree histograms (LDS packed)
    hist_src_kernel<<<HIST_BLOCKS, 256, 0, stream>>>(src, dump);
    // K2: reduce -> norm_out
    reduce_normout_kernel<<<(HWORDS + 255) / 256, 256, 0, stream>>>(dump, norm_out);
    // K3: bucket partition by dst range
    scatter_pairs_kernel<<<SCAT_BLOCKS, 256, 0, stream>>>(src, dst, bucket_cursor, pairbuf);
    // K4: bucket bases
    bucket_scan_kernel<<<1, NBUCKETS, 0, stream>>>(bucket_cursor, bucket_base);
    // K5: per-bucket counting sort -> row_ptr, norm_in, sorted_src
    sort_bucket_kernel<<<NBUCKETS, 256, 0, stream>>>(bucket_cursor, bucket_base, pairbuf,
                                                     row_ptr, norm_in, sorted_src);
    // K6: xs1 = x * norm_out   (runs after K2; dump region is dead by now)
    scale_kernel<<<(N_NODES * D + 255) / 256, 256, 0, stream>>>(x, norm_out, xs1);
    // K7: layer 1 -> xs2 = relu(h1)*norm_out (pre-scaled layer-2 messages)
    aggregate_kernel<1><<<(N_NODES + 7) / 8, 256, 0, stream>>>(row_ptr, sorted_src, xs1,
                                                               norm_in, norm_out, W1, b1, xs2);
    // K8: layer 2 -> final output
    aggregate_kernel<0><<<(N_NODES + 7) / 8, 256, 0, stream>>>(row_ptr, sorted_src, xs2,
                                                               norm_in, norm_out, W2, b2, out);
}